// Round 21
// baseline (32.000 us; speedup 1.0000x reference)
//
#include <hip/hip_runtime.h>
#include <hip/hip_bf16.h>

// Problem constants (match reference)
#define BB 16384
#define DD 512
#define NCLS 90
#define KC 32
#define BUCKET 512   // max samples per class (mean 182, +24 sigma headroom)
#define NP 4         // partition blocks per class (chunk = 32 samples) — R19 optimum

typedef __attribute__((ext_vector_type(8))) short short8;   // 8 bf16 (4 VGPRs)
typedef __attribute__((ext_vector_type(4))) float fx4;      // MFMA accumulator

// pack 8 f32 -> 8 bf16 (RNE, v_cvt_pk_bf16_f32), with / without scale
static __device__ __forceinline__ short8 pack8s(float sc, float4 a, float4 b) {
    union { __hip_bfloat162 h[4]; short8 s; } u;
    u.h[0] = __float22bfloat162_rn(make_float2(a.x * sc, a.y * sc));
    u.h[1] = __float22bfloat162_rn(make_float2(a.z * sc, a.w * sc));
    u.h[2] = __float22bfloat162_rn(make_float2(b.x * sc, b.y * sc));
    u.h[3] = __float22bfloat162_rn(make_float2(b.z * sc, b.w * sc));
    return u.s;
}
static __device__ __forceinline__ short8 pack8(float4 a, float4 b) {
    union { __hip_bfloat162 h[4]; short8 s; } u;
    u.h[0] = __float22bfloat162_rn(make_float2(a.x, a.y));
    u.h[1] = __float22bfloat162_rn(make_float2(a.z, a.w));
    u.h[2] = __float22bfloat162_rn(make_float2(b.x, b.y));
    u.h[3] = __float22bfloat162_rn(make_float2(b.z, b.w));
    return u.s;
}

// ------- K1: binning (R9's proven LDS-ballot block) + counter re-arm ---------
__global__ __launch_bounds__(1024)
void k_bin(const int* __restrict__ labels, int* __restrict__ idx, int* __restrict__ cnt,
           int* __restrict__ counter) {
    __shared__ int lab[BB];       // 64 KiB label cache
    __shared__ int wcnt[16];

    int t = threadIdx.x, w = t >> 6, lane = t & 63;
    int c = blockIdx.x;
    if (c == 0 && t == 0) *counter = 0;             // re-arm every call (replay-safe)
    for (int j = t; j < BB / 4; j += 1024)          // coalesced int4 load
        ((int4*)lab)[j] = ((const int4*)labels)[j];
    __syncthreads();

    int seg4 = w * (BB / 4 / 16);                   // 256 int4s per wave
    int cw = 0;
#pragma unroll
    for (int jj = 0; jj < 4; jj++) {
        int4 v = ((int4*)lab)[seg4 + jj * 64 + lane];
        cw += (v.x == c) + (v.y == c) + (v.z == c) + (v.w == c);
    }
#pragma unroll
    for (int m = 1; m < 64; m <<= 1) cw += __shfl_xor(cw, m, 64);
    if (lane == 0) wcnt[w] = cw;
    __syncthreads();
    int pos = c * BUCKET;
    for (int ww = 0; ww < w; ww++) pos += wcnt[ww];
#pragma unroll
    for (int jj = 0; jj < 4; jj++) {
        int4 v = ((int4*)lab)[seg4 + jj * 64 + lane];
        int gbase = (seg4 + jj * 64 + lane) * 4;
        { bool m = (v.x == c); unsigned long long k = __ballot(m);
          if (m) idx[pos + __popcll(k & ((1ull << lane) - 1ull))] = gbase;     pos += __popcll(k); }
        { bool m = (v.y == c); unsigned long long k = __ballot(m);
          if (m) idx[pos + __popcll(k & ((1ull << lane) - 1ull))] = gbase + 1; pos += __popcll(k); }
        { bool m = (v.z == c); unsigned long long k = __ballot(m);
          if (m) idx[pos + __popcll(k & ((1ull << lane) - 1ull))] = gbase + 2; pos += __popcll(k); }
        { bool m = (v.w == c); unsigned long long k = __ballot(m);
          if (m) idx[pos + __popcll(k & ((1ull << lane) - 1ull))] = gbase + 3; pos += __popcll(k); }
    }
    if (t == 0) {
        int s = 0;
#pragma unroll
        for (int i = 0; i < 16; i++) s += wcnt[i];
        cnt[c] = s;
    }
}

// ------- K2: main — R19-verbatim chunk pipeline + last-block final mean ------
__launch_bounds__(256, 2)
__global__ void k_main(const float* __restrict__ x,
                       const float* __restrict__ centers,
                       const int* __restrict__ cnt,
                       const int* __restrict__ idx,
                       float* __restrict__ partials,
                       int* __restrict__ counter,
                       float* __restrict__ out) {
    __shared__ __align__(16) short c_lds[KC * DD];   // 32 KiB bf16, XOR-swizzled
    __shared__ __align__(16) short x_lds[32 * DD];   // 32 KiB bf16, XOR-swizzled
    __shared__ float S_lds[32][33];
    __shared__ float xinv[32];
    __shared__ float red4[4];
    __shared__ int lastflag;

    int c = blockIdx.x >> 2;
    int p = blockIdx.x & 3;
    int n = cnt[c];
    int nch = (n + 31) >> 5;
    int t = threadIdx.x, w = t >> 6, lane = t & 63;
    float loss_acc = 0.f;

    if (p < nch) {
        int base = c * BUCKET;
        int row8 = t >> 3, l8 = t & 7;            // 8 threads per (sample|center) row
        int mrow = ((w & 1) << 4) + (lane & 15);
        int nrow = ((w >> 1) << 4) + (lane & 15);

        // ---- issue FIRST chunk's x loads (overlap with center norm below) ----
        float4 xva[8], xvb[8];
        {
            int off = p << 5;
            int rem = n - off;
            int r = (row8 < rem) ? row8 : (rem - 1);
            int g = idx[base + off + r];
            const float4* src = (const float4*)(x + (size_t)g * DD);
#pragma unroll
            for (int jj = 0; jj < 8; jj++) {
                xva[jj] = src[2 * l8 + 16 * jj];
                xvb[jj] = src[2 * l8 + 16 * jj + 1];
            }
        }

        // ---- center norm: batch-load 16 float4, norm, scale, pack, c_lds ----
        {
            const float4* csrc = (const float4*)(centers + ((size_t)c * KC + row8) * DD);
            float4 cva[8], cvb[8];
#pragma unroll
            for (int jj = 0; jj < 8; jj++) {
                cva[jj] = csrc[2 * l8 + 16 * jj];
                cvb[jj] = csrc[2 * l8 + 16 * jj + 1];
            }
            float s = 0.f;
#pragma unroll
            for (int jj = 0; jj < 8; jj++) {
                float4 a = cva[jj], b4 = cvb[jj];
                s += a.x * a.x + a.y * a.y + a.z * a.z + a.w * a.w
                   + b4.x * b4.x + b4.y * b4.y + b4.z * b4.z + b4.w * b4.w;
            }
#pragma unroll
            for (int m = 1; m < 8; m <<= 1) s += __shfl_xor(s, m, 64);
            float sc = rsqrtf(s + 1e-12f);
#pragma unroll
            for (int jj = 0; jj < 8; jj++) {
                int c16 = l8 + 8 * jj;             // 16B bf16 chunk 0..63
                *(short8*)&c_lds[row8 * DD + ((c16 ^ (row8 & 7)) << 3)]
                    = pack8s(sc, cva[jj], cvb[jj]);
            }
        }

        for (int ch = p; ch < nch; ch += NP) {
            int off = ch << 5;
            int rem = n - off;                    // > 0

            // ---- consume prefetched x: norm + cvt + x_lds ----
            {
                float nrm = 0.f;
#pragma unroll
                for (int jj = 0; jj < 8; jj++) {
                    int cc = l8 + 8 * jj;          // 16B bf16 chunk 0..63
                    float4 a = xva[jj], b4 = xvb[jj];
                    nrm += a.x * a.x + a.y * a.y + a.z * a.z + a.w * a.w
                         + b4.x * b4.x + b4.y * b4.y + b4.z * b4.z + b4.w * b4.w;
                    *(short8*)&x_lds[row8 * DD + ((cc ^ (row8 & 7)) << 3)] = pack8(a, b4);
                }
#pragma unroll
                for (int m = 1; m < 8; m <<= 1) nrm += __shfl_xor(nrm, m, 64);
                if (l8 == 0) xinv[row8] = rsqrtf(nrm + 1e-12f);
            }
            __syncthreads();                       // c_lds (1st iter) + x_lds ready

            // ---- MFMA: S[32 samples][32 k] in 4 wave-quadrants ----
            fx4 acc = {0.f, 0.f, 0.f, 0.f};
#pragma unroll
            for (int ks = 0; ks < 16; ks++) {
                int c16a = ks * 4 + (lane >> 4);
                short8 av = *(const short8*)&x_lds[mrow * DD + ((c16a ^ (mrow & 7)) << 3)];
                short8 bv = *(const short8*)&c_lds[nrow * DD + ((c16a ^ (nrow & 7)) << 3)];
                acc = __builtin_amdgcn_mfma_f32_16x16x32_bf16(av, bv, acc, 0, 0, 0);
            }
#pragma unroll
            for (int j = 0; j < 4; j++) {
                int r = ((w & 1) << 4) + ((lane >> 4) << 2) + j;   // C/D row
                int col = ((w >> 1) << 4) + (lane & 15);           // C/D col
                S_lds[r][col] = acc[j];
            }

            // ---- prefetch NEXT chunk's x into registers (survives barriers) --
            if (ch + NP < nch) {
                int off2 = (ch + NP) << 5;
                int rem2 = n - off2;
                int r2 = (row8 < rem2) ? row8 : (rem2 - 1);
                int g2 = idx[base + off2 + r2];
                const float4* src2 = (const float4*)(x + (size_t)g2 * DD);
#pragma unroll
                for (int jj = 0; jj < 8; jj++) {
                    xva[jj] = src2[2 * l8 + 16 * jj];
                    xvb[jj] = src2[2 * l8 + 16 * jj + 1];
                }
            }
            __syncthreads();                       // S_lds ready

            // ---- MAX-FREE softmax over K=32 (cos in [-1,1]; __expf) ----
            {
                float xv = xinv[row8];
                int q4 = l8 << 2;
                float s0 = S_lds[row8][q4 + 0] * xv;
                float s1 = S_lds[row8][q4 + 1] * xv;
                float s2 = S_lds[row8][q4 + 2] * xv;
                float s3 = S_lds[row8][q4 + 3] * xv;
                float e0 = __expf(s0), e1 = __expf(s1);
                float e2 = __expf(s2), e3 = __expf(s3);
                float Z = e0 + e1 + e2 + e3;
                float num = e0 * (1.f - s0) + e1 * (1.f - s1)
                          + e2 * (1.f - s2) + e3 * (1.f - s3);
#pragma unroll
                for (int m = 1; m < 8; m <<= 1) {
                    Z += __shfl_xor(Z, m, 64);
                    num += __shfl_xor(num, m, 64);
                }
                if (l8 == 0 && row8 < rem) loss_acc += num / Z;
            }
            __syncthreads();   // protect x_lds/S_lds before next chunk
        }
    }

    // ---- block partial + deterministic last-block final mean ----
#pragma unroll
    for (int m = 1; m < 64; m <<= 1) loss_acc += __shfl_xor(loss_acc, m, 64);
    if (lane == 0) red4[w] = loss_acc;
    __syncthreads();
    if (t == 0) {
        partials[blockIdx.x] = red4[0] + red4[1] + red4[2] + red4[3];
        __threadfence();                           // publish partial
        int old = atomicAdd(counter, 1);
        lastflag = (old == (int)gridDim.x - 1);
    }
    __syncthreads();
    if (lastflag) {
        __threadfence();
        float s = 0.f;
        for (int i = t; i < NCLS * NP; i += 256)   // fixed per-thread indices
            s += __hip_atomic_load(&partials[i], __ATOMIC_RELAXED, __HIP_MEMORY_SCOPE_AGENT);
#pragma unroll
        for (int m = 1; m < 64; m <<= 1) s += __shfl_xor(s, m, 64);
        if (lane == 0) red4[w] = s;
        __syncthreads();
        if (t == 0) out[0] = (red4[0] + red4[1] + red4[2] + red4[3]) * (1.0f / (float)BB);
    }
}

extern "C" void kernel_launch(void* const* d_in, const int* in_sizes, int n_in,
                              void* d_out, int out_size, void* d_ws, size_t ws_size,
                              hipStream_t stream) {
    const float* x       = (const float*)d_in[0];
    const int*   labels  = (const int*)d_in[1];
    const float* centers = (const float*)d_in[2];
    float* out = (float*)d_out;

    char* ws = (char*)d_ws;
    int*   idx      = (int*)(ws + 0);               // 90*512 ints = 184,320 B
    int*   cnt      = (int*)(ws + 184320);          // 90 ints
    int*   counter  = (int*)(ws + 184832);          // 1 int (re-armed by k_bin)
    float* partials = (float*)(ws + 196608);        // 360 floats (all written)

    k_bin<<<NCLS, 1024, 0, stream>>>(labels, idx, cnt, counter);
    k_main<<<NCLS * NP, 256, 0, stream>>>(x, centers, cnt, idx, partials, counter, out);
}

// Round 22
// 26.258 us; speedup vs baseline: 1.2187x; 1.2187x over previous
//
#include <hip/hip_runtime.h>
#include <hip/hip_bf16.h>

// Problem constants (match reference)
#define BB 16384
#define DD 512
#define NCLS 90
#define KC 32
#define BUCKET 512   // max samples per class (mean 182, +24 sigma headroom)
#define NP 5         // partition blocks per class: 450 blocks = one residency round

typedef __attribute__((ext_vector_type(8))) short short8;   // 8 bf16 (4 VGPRs)
typedef __attribute__((ext_vector_type(4))) float fx4;      // MFMA accumulator

// pack 8 f32 -> 8 bf16 (RNE, v_cvt_pk_bf16_f32), with / without scale
static __device__ __forceinline__ short8 pack8s(float sc, float4 a, float4 b) {
    union { __hip_bfloat162 h[4]; short8 s; } u;
    u.h[0] = __float22bfloat162_rn(make_float2(a.x * sc, a.y * sc));
    u.h[1] = __float22bfloat162_rn(make_float2(a.z * sc, a.w * sc));
    u.h[2] = __float22bfloat162_rn(make_float2(b.x * sc, b.y * sc));
    u.h[3] = __float22bfloat162_rn(make_float2(b.z * sc, b.w * sc));
    return u.s;
}
static __device__ __forceinline__ short8 pack8(float4 a, float4 b) {
    union { __hip_bfloat162 h[4]; short8 s; } u;
    u.h[0] = __float22bfloat162_rn(make_float2(a.x, a.y));
    u.h[1] = __float22bfloat162_rn(make_float2(a.z, a.w));
    u.h[2] = __float22bfloat162_rn(make_float2(b.x, b.y));
    u.h[3] = __float22bfloat162_rn(make_float2(b.z, b.w));
    return u.s;
}

// ------- K1: binning (R9's proven LDS-ballot block), 90 blocks ---------------
__global__ __launch_bounds__(1024)
void k_bin(const int* __restrict__ labels, int* __restrict__ idx, int* __restrict__ cnt) {
    __shared__ int lab[BB];       // 64 KiB label cache
    __shared__ int wcnt[16];

    int t = threadIdx.x, w = t >> 6, lane = t & 63;
    int c = blockIdx.x;
    for (int j = t; j < BB / 4; j += 1024)          // coalesced int4 load
        ((int4*)lab)[j] = ((const int4*)labels)[j];
    __syncthreads();

    int seg4 = w * (BB / 4 / 16);                   // 256 int4s per wave
    int cw = 0;
#pragma unroll
    for (int jj = 0; jj < 4; jj++) {
        int4 v = ((int4*)lab)[seg4 + jj * 64 + lane];
        cw += (v.x == c) + (v.y == c) + (v.z == c) + (v.w == c);
    }
#pragma unroll
    for (int m = 1; m < 64; m <<= 1) cw += __shfl_xor(cw, m, 64);
    if (lane == 0) wcnt[w] = cw;
    __syncthreads();
    int pos = c * BUCKET;
    for (int ww = 0; ww < w; ww++) pos += wcnt[ww];
#pragma unroll
    for (int jj = 0; jj < 4; jj++) {
        int4 v = ((int4*)lab)[seg4 + jj * 64 + lane];
        int gbase = (seg4 + jj * 64 + lane) * 4;
        { bool m = (v.x == c); unsigned long long k = __ballot(m);
          if (m) idx[pos + __popcll(k & ((1ull << lane) - 1ull))] = gbase;     pos += __popcll(k); }
        { bool m = (v.y == c); unsigned long long k = __ballot(m);
          if (m) idx[pos + __popcll(k & ((1ull << lane) - 1ull))] = gbase + 1; pos += __popcll(k); }
        { bool m = (v.z == c); unsigned long long k = __ballot(m);
          if (m) idx[pos + __popcll(k & ((1ull << lane) - 1ull))] = gbase + 2; pos += __popcll(k); }
        { bool m = (v.w == c); unsigned long long k = __ballot(m);
          if (m) idx[pos + __popcll(k & ((1ull << lane) - 1ull))] = gbase + 3; pos += __popcll(k); }
    }
    if (t == 0) {
        int s = 0;
#pragma unroll
        for (int i = 0; i < 16; i++) s += wcnt[i];
        cnt[c] = s;
    }
}

// ------- K2: main — R19-verbatim chunk pipeline, NP=5 ------------------------
__launch_bounds__(256, 2)
__global__ void k_main(const float* __restrict__ x,
                       const float* __restrict__ centers,
                       const int* __restrict__ cnt,
                       const int* __restrict__ idx,
                       float* __restrict__ partials) {
    __shared__ __align__(16) short c_lds[KC * DD];   // 32 KiB bf16, XOR-swizzled
    __shared__ __align__(16) short x_lds[32 * DD];   // 32 KiB bf16, XOR-swizzled
    __shared__ float S_lds[32][33];
    __shared__ float xinv[32];
    __shared__ float red4[4];

    int c = blockIdx.x / NP;
    int p = blockIdx.x % NP;
    int n = cnt[c];
    int nch = (n + 31) >> 5;
    int t = threadIdx.x, w = t >> 6, lane = t & 63;
    float loss_acc = 0.f;

    if (p < nch) {
        int base = c * BUCKET;
        int row8 = t >> 3, l8 = t & 7;            // 8 threads per (sample|center) row
        int mrow = ((w & 1) << 4) + (lane & 15);
        int nrow = ((w >> 1) << 4) + (lane & 15);

        // ---- issue FIRST chunk's x loads (overlap with center norm below) ----
        float4 xva[8], xvb[8];
        {
            int off = p << 5;
            int rem = n - off;
            int r = (row8 < rem) ? row8 : (rem - 1);
            int g = idx[base + off + r];
            const float4* src = (const float4*)(x + (size_t)g * DD);
#pragma unroll
            for (int jj = 0; jj < 8; jj++) {
                xva[jj] = src[2 * l8 + 16 * jj];
                xvb[jj] = src[2 * l8 + 16 * jj + 1];
            }
        }

        // ---- center norm: batch-load 16 float4, norm, scale, pack, c_lds ----
        {
            const float4* csrc = (const float4*)(centers + ((size_t)c * KC + row8) * DD);
            float4 cva[8], cvb[8];
#pragma unroll
            for (int jj = 0; jj < 8; jj++) {
                cva[jj] = csrc[2 * l8 + 16 * jj];
                cvb[jj] = csrc[2 * l8 + 16 * jj + 1];
            }
            float s = 0.f;
#pragma unroll
            for (int jj = 0; jj < 8; jj++) {
                float4 a = cva[jj], b4 = cvb[jj];
                s += a.x * a.x + a.y * a.y + a.z * a.z + a.w * a.w
                   + b4.x * b4.x + b4.y * b4.y + b4.z * b4.z + b4.w * b4.w;
            }
#pragma unroll
            for (int m = 1; m < 8; m <<= 1) s += __shfl_xor(s, m, 64);
            float sc = rsqrtf(s + 1e-12f);
#pragma unroll
            for (int jj = 0; jj < 8; jj++) {
                int c16 = l8 + 8 * jj;             // 16B bf16 chunk 0..63
                *(short8*)&c_lds[row8 * DD + ((c16 ^ (row8 & 7)) << 3)]
                    = pack8s(sc, cva[jj], cvb[jj]);
            }
        }

        for (int ch = p; ch < nch; ch += NP) {
            int off = ch << 5;
            int rem = n - off;                    // > 0

            // ---- consume prefetched x: norm + cvt + x_lds ----
            {
                float nrm = 0.f;
#pragma unroll
                for (int jj = 0; jj < 8; jj++) {
                    int cc = l8 + 8 * jj;          // 16B bf16 chunk 0..63
                    float4 a = xva[jj], b4 = xvb[jj];
                    nrm += a.x * a.x + a.y * a.y + a.z * a.z + a.w * a.w
                         + b4.x * b4.x + b4.y * b4.y + b4.z * b4.z + b4.w * b4.w;
                    *(short8*)&x_lds[row8 * DD + ((cc ^ (row8 & 7)) << 3)] = pack8(a, b4);
                }
#pragma unroll
                for (int m = 1; m < 8; m <<= 1) nrm += __shfl_xor(nrm, m, 64);
                if (l8 == 0) xinv[row8] = rsqrtf(nrm + 1e-12f);
            }
            __syncthreads();                       // c_lds (1st iter) + x_lds ready

            // ---- MFMA: S[32 samples][32 k] in 4 wave-quadrants ----
            fx4 acc = {0.f, 0.f, 0.f, 0.f};
#pragma unroll
            for (int ks = 0; ks < 16; ks++) {
                int c16a = ks * 4 + (lane >> 4);
                short8 av = *(const short8*)&x_lds[mrow * DD + ((c16a ^ (mrow & 7)) << 3)];
                short8 bv = *(const short8*)&c_lds[nrow * DD + ((c16a ^ (nrow & 7)) << 3)];
                acc = __builtin_amdgcn_mfma_f32_16x16x32_bf16(av, bv, acc, 0, 0, 0);
            }
#pragma unroll
            for (int j = 0; j < 4; j++) {
                int r = ((w & 1) << 4) + ((lane >> 4) << 2) + j;   // C/D row
                int col = ((w >> 1) << 4) + (lane & 15);           // C/D col
                S_lds[r][col] = acc[j];
            }

            // ---- prefetch NEXT chunk's x into registers (survives barriers) --
            if (ch + NP < nch) {
                int off2 = (ch + NP) << 5;
                int rem2 = n - off2;
                int r2 = (row8 < rem2) ? row8 : (rem2 - 1);
                int g2 = idx[base + off2 + r2];
                const float4* src2 = (const float4*)(x + (size_t)g2 * DD);
#pragma unroll
                for (int jj = 0; jj < 8; jj++) {
                    xva[jj] = src2[2 * l8 + 16 * jj];
                    xvb[jj] = src2[2 * l8 + 16 * jj + 1];
                }
            }
            __syncthreads();                       // S_lds ready

            // ---- MAX-FREE softmax over K=32 (cos in [-1,1]; __expf) ----
            {
                float xv = xinv[row8];
                int q4 = l8 << 2;
                float s0 = S_lds[row8][q4 + 0] * xv;
                float s1 = S_lds[row8][q4 + 1] * xv;
                float s2 = S_lds[row8][q4 + 2] * xv;
                float s3 = S_lds[row8][q4 + 3] * xv;
                float e0 = __expf(s0), e1 = __expf(s1);
                float e2 = __expf(s2), e3 = __expf(s3);
                float Z = e0 + e1 + e2 + e3;
                float num = e0 * (1.f - s0) + e1 * (1.f - s1)
                          + e2 * (1.f - s2) + e3 * (1.f - s3);
#pragma unroll
                for (int m = 1; m < 8; m <<= 1) {
                    Z += __shfl_xor(Z, m, 64);
                    num += __shfl_xor(num, m, 64);
                }
                if (l8 == 0 && row8 < rem) loss_acc += num / Z;
            }
            __syncthreads();   // protect x_lds/S_lds before next chunk
        }
    }

    // ---- slim per-wave tail reduce (1 barrier) ----
#pragma unroll
    for (int m = 1; m < 64; m <<= 1) loss_acc += __shfl_xor(loss_acc, m, 64);
    if (lane == 0) red4[w] = loss_acc;
    __syncthreads();
    if (t == 0) partials[blockIdx.x] = red4[0] + red4[1] + red4[2] + red4[3];
}

// ------- K3: deterministic final mean over 450 block partials ----------------
__global__ void k_final(const float* __restrict__ partials, float* __restrict__ out) {
    __shared__ float red[256];
    int t = threadIdx.x;
    float s = 0.f;
    for (int i = t; i < NCLS * NP; i += 256) s += partials[i];
    red[t] = s;
    __syncthreads();
    for (int h = 128; h > 0; h >>= 1) {
        if (t < h) red[t] += red[t + h];
        __syncthreads();
    }
    if (t == 0) out[0] = red[0] * (1.0f / (float)BB);
}

extern "C" void kernel_launch(void* const* d_in, const int* in_sizes, int n_in,
                              void* d_out, int out_size, void* d_ws, size_t ws_size,
                              hipStream_t stream) {
    const float* x       = (const float*)d_in[0];
    const int*   labels  = (const int*)d_in[1];
    const float* centers = (const float*)d_in[2];
    float* out = (float*)d_out;

    char* ws = (char*)d_ws;
    int*   idx      = (int*)(ws + 0);               // 90*512 ints = 184,320 B
    int*   cnt      = (int*)(ws + 184320);          // 90 ints
    float* partials = (float*)(ws + 196608);        // 450 floats (all written)

    k_bin<<<NCLS, 1024, 0, stream>>>(labels, idx, cnt);
    k_main<<<NCLS * NP, 256, 0, stream>>>(x, centers, cnt, idx, partials);
    k_final<<<1, 256, 0, stream>>>(partials, out);
}

// Round 23
// 24.953 us; speedup vs baseline: 1.2824x; 1.0523x over previous
//
#include <hip/hip_runtime.h>
#include <hip/hip_bf16.h>

// Problem constants (match reference)
#define BB 16384
#define DD 512
#define NCLS 90
#define KC 32
#define BUCKET 512   // max samples per class (mean 182, +24 sigma headroom)
#define NP 4         // partition blocks per class (chunk = 32 samples) — optimum

typedef __attribute__((ext_vector_type(8))) short short8;   // 8 bf16 (4 VGPRs)
typedef __attribute__((ext_vector_type(4))) float fx4;      // MFMA accumulator

// pack 8 f32 -> 8 bf16 (RNE, v_cvt_pk_bf16_f32), with / without scale
static __device__ __forceinline__ short8 pack8s(float sc, float4 a, float4 b) {
    union { __hip_bfloat162 h[4]; short8 s; } u;
    u.h[0] = __float22bfloat162_rn(make_float2(a.x * sc, a.y * sc));
    u.h[1] = __float22bfloat162_rn(make_float2(a.z * sc, a.w * sc));
    u.h[2] = __float22bfloat162_rn(make_float2(b.x * sc, b.y * sc));
    u.h[3] = __float22bfloat162_rn(make_float2(b.z * sc, b.w * sc));
    return u.s;
}
static __device__ __forceinline__ short8 pack8(float4 a, float4 b) {
    union { __hip_bfloat162 h[4]; short8 s; } u;
    u.h[0] = __float22bfloat162_rn(make_float2(a.x, a.y));
    u.h[1] = __float22bfloat162_rn(make_float2(a.z, a.w));
    u.h[2] = __float22bfloat162_rn(make_float2(b.x, b.y));
    u.h[3] = __float22bfloat162_rn(make_float2(b.z, b.w));
    return u.s;
}
static __device__ __forceinline__ void gload_lds16(const void* g, void* l) {
    __builtin_amdgcn_global_load_lds(
        (const __attribute__((address_space(1))) void*)g,
        (__attribute__((address_space(3))) void*)l, 16, 0, 0);
}

// ------- K1: binning + class-center normalization (overlapped) ---------------
// One block per class. Center loads (regs) and label loads (LDS) issued
// back-to-back -> both latency rounds overlap. Norm+cni write fills the
// wait for labels; scans (R9-proven ballot compaction) follow.
__global__ __launch_bounds__(1024)
void k_bin(const int* __restrict__ labels, const float* __restrict__ centers,
           short* __restrict__ cni, int* __restrict__ idx, int* __restrict__ cnt) {
    __shared__ int lab[BB];       // 64 KiB label cache
    __shared__ int wcnt[16];

    int t = threadIdx.x, w = t >> 6, lane = t & 63;
    int c = blockIdx.x;

    // ---- issue center loads: row r = t>>5 (0..31), 32 threads/row ----
    int r = t >> 5, s = t & 31;                     // s: 32B sub-chunk of row
    const float4* csrc = (const float4*)(centers + ((size_t)c * KC + r) * DD);
    float4 cv0 = csrc[4 * s + 0], cv1 = csrc[4 * s + 1];
    float4 cv2 = csrc[4 * s + 2], cv3 = csrc[4 * s + 3];

    // ---- issue label loads into LDS (concurrent with center loads) ----
    for (int j = t; j < BB / 4; j += 1024)          // coalesced int4 load
        ((int4*)lab)[j] = ((const int4*)labels)[j];

    // ---- norm + scale + bf16 cni write (fills label-load latency) ----
    {
        float nr = cv0.x * cv0.x + cv0.y * cv0.y + cv0.z * cv0.z + cv0.w * cv0.w
                 + cv1.x * cv1.x + cv1.y * cv1.y + cv1.z * cv1.z + cv1.w * cv1.w
                 + cv2.x * cv2.x + cv2.y * cv2.y + cv2.z * cv2.z + cv2.w * cv2.w
                 + cv3.x * cv3.x + cv3.y * cv3.y + cv3.z * cv3.z + cv3.w * cv3.w;
#pragma unroll
        for (int m = 1; m < 32; m <<= 1) nr += __shfl_xor(nr, m, 64);  // 32-lane halves
        float sc = rsqrtf(nr + 1e-12f);
        short* dst = cni + ((size_t)c * KC + r) * DD + s * 16;   // plain layout
        *(short8*)(dst)     = pack8s(sc, cv0, cv1);
        *(short8*)(dst + 8) = pack8s(sc, cv2, cv3);
    }
    __syncthreads();

    // ---- pass 1: count ----
    int seg4 = w * (BB / 4 / 16);                   // 256 int4s per wave
    int cw = 0;
#pragma unroll
    for (int jj = 0; jj < 4; jj++) {
        int4 v = ((int4*)lab)[seg4 + jj * 64 + lane];
        cw += (v.x == c) + (v.y == c) + (v.z == c) + (v.w == c);
    }
#pragma unroll
    for (int m = 1; m < 64; m <<= 1) cw += __shfl_xor(cw, m, 64);
    if (lane == 0) wcnt[w] = cw;
    __syncthreads();
    int pos = c * BUCKET;
    for (int ww = 0; ww < w; ww++) pos += wcnt[ww];
    // ---- pass 2: ballot-compaction emit (deterministic order) ----
#pragma unroll
    for (int jj = 0; jj < 4; jj++) {
        int4 v = ((int4*)lab)[seg4 + jj * 64 + lane];
        int gbase = (seg4 + jj * 64 + lane) * 4;
        { bool m = (v.x == c); unsigned long long k = __ballot(m);
          if (m) idx[pos + __popcll(k & ((1ull << lane) - 1ull))] = gbase;     pos += __popcll(k); }
        { bool m = (v.y == c); unsigned long long k = __ballot(m);
          if (m) idx[pos + __popcll(k & ((1ull << lane) - 1ull))] = gbase + 1; pos += __popcll(k); }
        { bool m = (v.z == c); unsigned long long k = __ballot(m);
          if (m) idx[pos + __popcll(k & ((1ull << lane) - 1ull))] = gbase + 2; pos += __popcll(k); }
        { bool m = (v.w == c); unsigned long long k = __ballot(m);
          if (m) idx[pos + __popcll(k & ((1ull << lane) - 1ull))] = gbase + 3; pos += __popcll(k); }
    }
    if (t == 0) {
        int ssum = 0;
#pragma unroll
        for (int i = 0; i < 16; i++) ssum += wcnt[i];
        cnt[c] = ssum;
    }
}

// ------- K2: main — DMA c_lds prologue + R19 chunk pipeline (NP=4) -----------
__launch_bounds__(256, 2)
__global__ void k_main(const float* __restrict__ x,
                       const short* __restrict__ cni,
                       const int* __restrict__ cnt,
                       const int* __restrict__ idx,
                       float* __restrict__ partials) {
    __shared__ __align__(16) short c_lds[KC * DD];   // 32 KiB bf16, XOR-swizzled
    __shared__ __align__(16) short x_lds[32 * DD];   // 32 KiB bf16, XOR-swizzled
    __shared__ float S_lds[32][33];
    __shared__ float xinv[32];
    __shared__ float red4[4];

    int c = blockIdx.x >> 2;
    int p = blockIdx.x & 3;
    int n = cnt[c];
    int nch = (n + 31) >> 5;
    int t = threadIdx.x, w = t >> 6, lane = t & 63;
    float loss_acc = 0.f;

    if (p < nch) {
        int base = c * BUCKET;
        int row8 = t >> 3, l8 = t & 7;            // 8 threads per sample row
        int mrow = ((w & 1) << 4) + (lane & 15);
        int nrow = ((w >> 1) << 4) + (lane & 15);

        // ---- prologue: 8 async DMA c_lds stages + first-chunk x loads, ----
        // ---- ALL in flight before the first barrier (no VALU prologue) ----
        const short* cbase = cni + (size_t)c * KC * DD;
#pragma unroll
        for (int it = 0; it < 8; it++) {
            int q = t + 256 * it;                 // 16B chunk 0..2047, linear LDS
            int drow = q >> 6, cc = q & 63;
            gload_lds16(cbase + drow * DD + (cc ^ (drow & 7)) * 8, &c_lds[q * 8]);
        }
        float4 xva[8], xvb[8];
        {
            int off = p << 5;
            int rem = n - off;
            int r = (row8 < rem) ? row8 : (rem - 1);
            int g = idx[base + off + r];
            const float4* src = (const float4*)(x + (size_t)g * DD);
#pragma unroll
            for (int jj = 0; jj < 8; jj++) {
                xva[jj] = src[2 * l8 + 16 * jj];
                xvb[jj] = src[2 * l8 + 16 * jj + 1];
            }
        }

        for (int ch = p; ch < nch; ch += NP) {
            int off = ch << 5;
            int rem = n - off;                    // > 0

            // ---- consume prefetched x: norm + cvt + x_lds ----
            {
                float nrm = 0.f;
#pragma unroll
                for (int jj = 0; jj < 8; jj++) {
                    int cc = l8 + 8 * jj;          // 16B bf16 chunk 0..63
                    float4 a = xva[jj], b4 = xvb[jj];
                    nrm += a.x * a.x + a.y * a.y + a.z * a.z + a.w * a.w
                         + b4.x * b4.x + b4.y * b4.y + b4.z * b4.z + b4.w * b4.w;
                    *(short8*)&x_lds[row8 * DD + ((cc ^ (row8 & 7)) << 3)] = pack8(a, b4);
                }
#pragma unroll
                for (int m = 1; m < 8; m <<= 1) nrm += __shfl_xor(nrm, m, 64);
                if (l8 == 0) xinv[row8] = rsqrtf(nrm + 1e-12f);
            }
            __syncthreads();                       // drains c_lds DMA + x_lds writes

            // ---- MFMA: S[32 samples][32 k] in 4 wave-quadrants ----
            fx4 acc = {0.f, 0.f, 0.f, 0.f};
#pragma unroll
            for (int ks = 0; ks < 16; ks++) {
                int c16a = ks * 4 + (lane >> 4);
                short8 av = *(const short8*)&x_lds[mrow * DD + ((c16a ^ (mrow & 7)) << 3)];
                short8 bv = *(const short8*)&c_lds[nrow * DD + ((c16a ^ (nrow & 7)) << 3)];
                acc = __builtin_amdgcn_mfma_f32_16x16x32_bf16(av, bv, acc, 0, 0, 0);
            }
#pragma unroll
            for (int j = 0; j < 4; j++) {
                int r = ((w & 1) << 4) + ((lane >> 4) << 2) + j;   // C/D row
                int col = ((w >> 1) << 4) + (lane & 15);           // C/D col
                S_lds[r][col] = acc[j];
            }

            // ---- prefetch NEXT chunk's x into registers (survives barriers) --
            if (ch + NP < nch) {
                int off2 = (ch + NP) << 5;
                int rem2 = n - off2;
                int r2 = (row8 < rem2) ? row8 : (rem2 - 1);
                int g2 = idx[base + off2 + r2];
                const float4* src2 = (const float4*)(x + (size_t)g2 * DD);
#pragma unroll
                for (int jj = 0; jj < 8; jj++) {
                    xva[jj] = src2[2 * l8 + 16 * jj];
                    xvb[jj] = src2[2 * l8 + 16 * jj + 1];
                }
            }
            __syncthreads();                       // S_lds ready

            // ---- MAX-FREE softmax over K=32 (cos in [-1,1]; __expf) ----
            {
                float xv = xinv[row8];
                int q4 = l8 << 2;
                float s0 = S_lds[row8][q4 + 0] * xv;
                float s1 = S_lds[row8][q4 + 1] * xv;
                float s2 = S_lds[row8][q4 + 2] * xv;
                float s3 = S_lds[row8][q4 + 3] * xv;
                float e0 = __expf(s0), e1 = __expf(s1);
                float e2 = __expf(s2), e3 = __expf(s3);
                float Z = e0 + e1 + e2 + e3;
                float num = e0 * (1.f - s0) + e1 * (1.f - s1)
                          + e2 * (1.f - s2) + e3 * (1.f - s3);
#pragma unroll
                for (int m = 1; m < 8; m <<= 1) {
                    Z += __shfl_xor(Z, m, 64);
                    num += __shfl_xor(num, m, 64);
                }
                if (l8 == 0 && row8 < rem) loss_acc += num / Z;
            }
            __syncthreads();   // protect x_lds/S_lds before next chunk
        }
    }

    // ---- slim per-wave tail reduce (1 barrier) ----
#pragma unroll
    for (int m = 1; m < 64; m <<= 1) loss_acc += __shfl_xor(loss_acc, m, 64);
    if (lane == 0) red4[w] = loss_acc;
    __syncthreads();
    if (t == 0) partials[blockIdx.x] = red4[0] + red4[1] + red4[2] + red4[3];
}

// ------- K3: deterministic final mean over 360 block partials ----------------
__global__ void k_final(const float* __restrict__ partials, float* __restrict__ out) {
    __shared__ float red[256];
    int t = threadIdx.x;
    float s = 0.f;
    for (int i = t; i < NCLS * NP; i += 256) s += partials[i];
    red[t] = s;
    __syncthreads();
    for (int h = 128; h > 0; h >>= 1) {
        if (t < h) red[t] += red[t + h];
        __syncthreads();
    }
    if (t == 0) out[0] = red[0] * (1.0f / (float)BB);
}

extern "C" void kernel_launch(void* const* d_in, const int* in_sizes, int n_in,
                              void* d_out, int out_size, void* d_ws, size_t ws_size,
                              hipStream_t stream) {
    const float* x       = (const float*)d_in[0];
    const int*   labels  = (const int*)d_in[1];
    const float* centers = (const float*)d_in[2];
    float* out = (float*)d_out;

    char* ws = (char*)d_ws;
    short* cni      = (short*)(ws + 0);             // 2880*512 bf16 = 2,949,120 B
    int*   idx      = (int*)(ws + 3145728);         // 90*512 ints   =   184,320 B
    int*   cnt      = (int*)(ws + 3407872);         // 90 ints
    float* partials = (float*)(ws + 3473408);       // 360 floats (all written)

    k_bin<<<NCLS, 1024, 0, stream>>>(labels, centers, cni, idx, cnt);
    k_main<<<NCLS * NP, 256, 0, stream>>>(x, cni, cnt, idx, partials);
    k_final<<<1, 256, 0, stream>>>(partials, out);
}

// Round 24
// 24.875 us; speedup vs baseline: 1.2864x; 1.0031x over previous
//
#include <hip/hip_runtime.h>
#include <hip/hip_bf16.h>

// Problem constants (match reference)
#define BB 16384
#define DD 512
#define NCLS 90
#define KC 32
#define NP 4         // partition blocks per class (chunk = 32 samples) — optimum

typedef __attribute__((ext_vector_type(8))) short short8;   // 8 bf16 (4 VGPRs)
typedef __attribute__((ext_vector_type(4))) float fx4;      // MFMA accumulator

// pack 8 f32 -> 8 bf16 (RNE, v_cvt_pk_bf16_f32), with / without scale
static __device__ __forceinline__ short8 pack8s(float sc, float4 a, float4 b) {
    union { __hip_bfloat162 h[4]; short8 s; } u;
    u.h[0] = __float22bfloat162_rn(make_float2(a.x * sc, a.y * sc));
    u.h[1] = __float22bfloat162_rn(make_float2(a.z * sc, a.w * sc));
    u.h[2] = __float22bfloat162_rn(make_float2(b.x * sc, b.y * sc));
    u.h[3] = __float22bfloat162_rn(make_float2(b.z * sc, b.w * sc));
    return u.s;
}
static __device__ __forceinline__ short8 pack8(float4 a, float4 b) {
    union { __hip_bfloat162 h[4]; short8 s; } u;
    u.h[0] = __float22bfloat162_rn(make_float2(a.x, a.y));
    u.h[1] = __float22bfloat162_rn(make_float2(a.z, a.w));
    u.h[2] = __float22bfloat162_rn(make_float2(b.x, b.y));
    u.h[3] = __float22bfloat162_rn(make_float2(b.z, b.w));
    return u.s;
}

// ---- K1: main — self-binning (redundant per block, overlapped) + R19 loop ---
// grid = 360 (4 blocks/class). Each block: issue its 16 center float4 loads,
// then ballot-scan ALL labels for class c into idx_lds (wave-segmented, two
// passes over L2-hot labels — R11-proven code), then center norm (loads have
// landed), then R19's chunk pipeline with register prefetch.
__launch_bounds__(256, 2)
__global__ void k_main(const float* __restrict__ x,
                       const float* __restrict__ centers,
                       const int* __restrict__ labels,
                       float* __restrict__ partials) {
    __shared__ __align__(16) short c_lds[KC * DD];   // 32 KiB bf16, XOR-swizzled
    __shared__ __align__(16) short x_lds[32 * DD];   // 32 KiB bf16, XOR-swizzled
    __shared__ float S_lds[32][33];
    __shared__ float xinv[32];
    __shared__ float red4[4];
    __shared__ int idx_lds[512];                     // class-c sample indices
    __shared__ int wcnt[4];

    int c = blockIdx.x >> 2;
    int p = blockIdx.x & 3;
    int t = threadIdx.x, w = t >> 6, lane = t & 63;
    int row8 = t >> 3, l8 = t & 7;                   // 8 threads per row

    // ---- issue this block's center loads FIRST (land during the scan) ----
    const float4* csrc = (const float4*)(centers + ((size_t)c * KC + row8) * DD);
    float4 cva[8], cvb[8];
#pragma unroll
    for (int jj = 0; jj < 8; jj++) {
        cva[jj] = csrc[2 * l8 + 16 * jj];
        cvb[jj] = csrc[2 * l8 + 16 * jj + 1];
    }

    // ---- self-bin class c: wave-segmented ballot compaction (R11-proven) ----
    int seg4 = w * (BB / 4 / 4);                     // 1024 int4 per wave
    {
        int cw = 0;
#pragma unroll
        for (int jj = 0; jj < 16; jj++) {
            int4 v = ((const int4*)labels)[seg4 + jj * 64 + lane];
            cw += (v.x == c) + (v.y == c) + (v.z == c) + (v.w == c);
        }
#pragma unroll
        for (int m = 1; m < 64; m <<= 1) cw += __shfl_xor(cw, m, 64);
        if (lane == 0) wcnt[w] = cw;
    }
    __syncthreads();
    int n = wcnt[0] + wcnt[1] + wcnt[2] + wcnt[3];
    {
        int pos = 0;
        for (int ww = 0; ww < w; ww++) pos += wcnt[ww];
#pragma unroll
        for (int jj = 0; jj < 16; jj++) {            // re-read: L1/L2-hot
            int4 v = ((const int4*)labels)[seg4 + jj * 64 + lane];
            int gbase = (seg4 + jj * 64 + lane) * 4;
            { bool m = (v.x == c); unsigned long long k = __ballot(m);
              if (m) idx_lds[pos + __popcll(k & ((1ull << lane) - 1ull))] = gbase;     pos += __popcll(k); }
            { bool m = (v.y == c); unsigned long long k = __ballot(m);
              if (m) idx_lds[pos + __popcll(k & ((1ull << lane) - 1ull))] = gbase + 1; pos += __popcll(k); }
            { bool m = (v.z == c); unsigned long long k = __ballot(m);
              if (m) idx_lds[pos + __popcll(k & ((1ull << lane) - 1ull))] = gbase + 2; pos += __popcll(k); }
            { bool m = (v.w == c); unsigned long long k = __ballot(m);
              if (m) idx_lds[pos + __popcll(k & ((1ull << lane) - 1ull))] = gbase + 3; pos += __popcll(k); }
        }
    }
    __syncthreads();                                 // idx_lds ready

    int nch = (n + 31) >> 5;
    float loss_acc = 0.f;

    if (p < nch) {
        int mrow = ((w & 1) << 4) + (lane & 15);
        int nrow = ((w >> 1) << 4) + (lane & 15);

        // ---- issue FIRST chunk's x loads (overlap with center norm below) ----
        float4 xva[8], xvb[8];
        {
            int off = p << 5;
            int rem = n - off;
            int r = (row8 < rem) ? row8 : (rem - 1);
            int g = idx_lds[off + r];
            const float4* src = (const float4*)(x + (size_t)g * DD);
#pragma unroll
            for (int jj = 0; jj < 8; jj++) {
                xva[jj] = src[2 * l8 + 16 * jj];
                xvb[jj] = src[2 * l8 + 16 * jj + 1];
            }
        }

        // ---- center norm: regs already loaded; norm, scale, pack, c_lds ----
        {
            float s = 0.f;
#pragma unroll
            for (int jj = 0; jj < 8; jj++) {
                float4 a = cva[jj], b4 = cvb[jj];
                s += a.x * a.x + a.y * a.y + a.z * a.z + a.w * a.w
                   + b4.x * b4.x + b4.y * b4.y + b4.z * b4.z + b4.w * b4.w;
            }
#pragma unroll
            for (int m = 1; m < 8; m <<= 1) s += __shfl_xor(s, m, 64);
            float sc = rsqrtf(s + 1e-12f);
#pragma unroll
            for (int jj = 0; jj < 8; jj++) {
                int c16 = l8 + 8 * jj;               // 16B bf16 chunk 0..63
                *(short8*)&c_lds[row8 * DD + ((c16 ^ (row8 & 7)) << 3)]
                    = pack8s(sc, cva[jj], cvb[jj]);
            }
        }

        for (int ch = p; ch < nch; ch += NP) {
            int off = ch << 5;
            int rem = n - off;                       // > 0

            // ---- consume prefetched x: norm + cvt + x_lds ----
            {
                float nrm = 0.f;
#pragma unroll
                for (int jj = 0; jj < 8; jj++) {
                    int cc = l8 + 8 * jj;            // 16B bf16 chunk 0..63
                    float4 a = xva[jj], b4 = xvb[jj];
                    nrm += a.x * a.x + a.y * a.y + a.z * a.z + a.w * a.w
                         + b4.x * b4.x + b4.y * b4.y + b4.z * b4.z + b4.w * b4.w;
                    *(short8*)&x_lds[row8 * DD + ((cc ^ (row8 & 7)) << 3)] = pack8(a, b4);
                }
#pragma unroll
                for (int m = 1; m < 8; m <<= 1) nrm += __shfl_xor(nrm, m, 64);
                if (l8 == 0) xinv[row8] = rsqrtf(nrm + 1e-12f);
            }
            __syncthreads();                         // c_lds (1st iter) + x_lds ready

            // ---- MFMA: S[32 samples][32 k] in 4 wave-quadrants ----
            fx4 acc = {0.f, 0.f, 0.f, 0.f};
#pragma unroll
            for (int ks = 0; ks < 16; ks++) {
                int c16a = ks * 4 + (lane >> 4);
                short8 av = *(const short8*)&x_lds[mrow * DD + ((c16a ^ (mrow & 7)) << 3)];
                short8 bv = *(const short8*)&c_lds[nrow * DD + ((c16a ^ (nrow & 7)) << 3)];
                acc = __builtin_amdgcn_mfma_f32_16x16x32_bf16(av, bv, acc, 0, 0, 0);
            }
#pragma unroll
            for (int j = 0; j < 4; j++) {
                int r = ((w & 1) << 4) + ((lane >> 4) << 2) + j;   // C/D row
                int col = ((w >> 1) << 4) + (lane & 15);           // C/D col
                S_lds[r][col] = acc[j];
            }

            // ---- prefetch NEXT chunk's x into registers (survives barriers) --
            if (ch + NP < nch) {
                int off2 = (ch + NP) << 5;
                int rem2 = n - off2;
                int r2 = (row8 < rem2) ? row8 : (rem2 - 1);
                int g2 = idx_lds[off2 + r2];
                const float4* src2 = (const float4*)(x + (size_t)g2 * DD);
#pragma unroll
                for (int jj = 0; jj < 8; jj++) {
                    xva[jj] = src2[2 * l8 + 16 * jj];
                    xvb[jj] = src2[2 * l8 + 16 * jj + 1];
                }
            }
            __syncthreads();                         // S_lds ready

            // ---- MAX-FREE softmax over K=32 (cos in [-1,1]; __expf) ----
            {
                float xv = xinv[row8];
                int q4 = l8 << 2;
                float s0 = S_lds[row8][q4 + 0] * xv;
                float s1 = S_lds[row8][q4 + 1] * xv;
                float s2 = S_lds[row8][q4 + 2] * xv;
                float s3 = S_lds[row8][q4 + 3] * xv;
                float e0 = __expf(s0), e1 = __expf(s1);
                float e2 = __expf(s2), e3 = __expf(s3);
                float Z = e0 + e1 + e2 + e3;
                float num = e0 * (1.f - s0) + e1 * (1.f - s1)
                          + e2 * (1.f - s2) + e3 * (1.f - s3);
#pragma unroll
                for (int m = 1; m < 8; m <<= 1) {
                    Z += __shfl_xor(Z, m, 64);
                    num += __shfl_xor(num, m, 64);
                }
                if (l8 == 0 && row8 < rem) loss_acc += num / Z;
            }
            __syncthreads();   // protect x_lds/S_lds before next chunk
        }
    }

    // ---- slim per-wave tail reduce (1 barrier) ----
#pragma unroll
    for (int m = 1; m < 64; m <<= 1) loss_acc += __shfl_xor(loss_acc, m, 64);
    if (lane == 0) red4[w] = loss_acc;
    __syncthreads();
    if (t == 0) partials[blockIdx.x] = red4[0] + red4[1] + red4[2] + red4[3];
}

// ---- K2: deterministic final mean over 360 block partials -------------------
__global__ void k_final(const float* __restrict__ partials, float* __restrict__ out) {
    __shared__ float red[256];
    int t = threadIdx.x;
    float s = 0.f;
    for (int i = t; i < NCLS * NP; i += 256) s += partials[i];
    red[t] = s;
    __syncthreads();
    for (int h = 128; h > 0; h >>= 1) {
        if (t < h) red[t] += red[t + h];
        __syncthreads();
    }
    if (t == 0) out[0] = red[0] * (1.0f / (float)BB);
}

extern "C" void kernel_launch(void* const* d_in, const int* in_sizes, int n_in,
                              void* d_out, int out_size, void* d_ws, size_t ws_size,
                              hipStream_t stream) {
    const float* x       = (const float*)d_in[0];
    const int*   labels  = (const int*)d_in[1];
    const float* centers = (const float*)d_in[2];
    float* out = (float*)d_out;

    float* partials = (float*)d_ws;                  // 360 floats (all written)

    k_main<<<NCLS * NP, 256, 0, stream>>>(x, centers, labels, partials);
    k_final<<<1, 256, 0, stream>>>(partials, out);
}

// Round 25
// 24.720 us; speedup vs baseline: 1.2945x; 1.0063x over previous
//
#include <hip/hip_runtime.h>
#include <hip/hip_bf16.h>

// Problem constants (match reference)
#define BB 16384
#define DD 512
#define NCLS 90
#define KC 32
#define BUCKET 512   // max samples per class (mean 182, +24 sigma headroom)
#define NP 4         // partition blocks per class (chunk = 32 samples) — optimum

typedef __attribute__((ext_vector_type(8))) short short8;   // 8 bf16 (4 VGPRs)
typedef __attribute__((ext_vector_type(4))) float fx4;      // MFMA accumulator

// pack 8 f32 -> 8 bf16 (RNE, v_cvt_pk_bf16_f32), with / without scale
static __device__ __forceinline__ short8 pack8s(float sc, float4 a, float4 b) {
    union { __hip_bfloat162 h[4]; short8 s; } u;
    u.h[0] = __float22bfloat162_rn(make_float2(a.x * sc, a.y * sc));
    u.h[1] = __float22bfloat162_rn(make_float2(a.z * sc, a.w * sc));
    u.h[2] = __float22bfloat162_rn(make_float2(b.x * sc, b.y * sc));
    u.h[3] = __float22bfloat162_rn(make_float2(b.z * sc, b.w * sc));
    return u.s;
}
static __device__ __forceinline__ short8 pack8(float4 a, float4 b) {
    union { __hip_bfloat162 h[4]; short8 s; } u;
    u.h[0] = __float22bfloat162_rn(make_float2(a.x, a.y));
    u.h[1] = __float22bfloat162_rn(make_float2(a.z, a.w));
    u.h[2] = __float22bfloat162_rn(make_float2(b.x, b.y));
    u.h[3] = __float22bfloat162_rn(make_float2(b.z, b.w));
    return u.s;
}

// ------- K1: binning ONLY (R9's proven LDS-ballot block), 90 blocks ----------
__global__ __launch_bounds__(1024)
void k_bin(const int* __restrict__ labels, int* __restrict__ idx, int* __restrict__ cnt) {
    __shared__ int lab[BB];       // 64 KiB label cache
    __shared__ int wcnt[16];

    int t = threadIdx.x, w = t >> 6, lane = t & 63;
    int c = blockIdx.x;
    for (int j = t; j < BB / 4; j += 1024)          // coalesced int4 load
        ((int4*)lab)[j] = ((const int4*)labels)[j];
    __syncthreads();

    int seg4 = w * (BB / 4 / 16);                   // 256 int4s per wave
    int cw = 0;
#pragma unroll
    for (int jj = 0; jj < 4; jj++) {
        int4 v = ((int4*)lab)[seg4 + jj * 64 + lane];
        cw += (v.x == c) + (v.y == c) + (v.z == c) + (v.w == c);
    }
#pragma unroll
    for (int m = 1; m < 64; m <<= 1) cw += __shfl_xor(cw, m, 64);
    if (lane == 0) wcnt[w] = cw;
    __syncthreads();
    int pos = c * BUCKET;
    for (int ww = 0; ww < w; ww++) pos += wcnt[ww];
#pragma unroll
    for (int jj = 0; jj < 4; jj++) {
        int4 v = ((int4*)lab)[seg4 + jj * 64 + lane];
        int gbase = (seg4 + jj * 64 + lane) * 4;
        { bool m = (v.x == c); unsigned long long k = __ballot(m);
          if (m) idx[pos + __popcll(k & ((1ull << lane) - 1ull))] = gbase;     pos += __popcll(k); }
        { bool m = (v.y == c); unsigned long long k = __ballot(m);
          if (m) idx[pos + __popcll(k & ((1ull << lane) - 1ull))] = gbase + 1; pos += __popcll(k); }
        { bool m = (v.z == c); unsigned long long k = __ballot(m);
          if (m) idx[pos + __popcll(k & ((1ull << lane) - 1ull))] = gbase + 2; pos += __popcll(k); }
        { bool m = (v.w == c); unsigned long long k = __ballot(m);
          if (m) idx[pos + __popcll(k & ((1ull << lane) - 1ull))] = gbase + 3; pos += __popcll(k); }
    }
    if (t == 0) {
        int s = 0;
#pragma unroll
        for (int i = 0; i < 16; i++) s += wcnt[i];
        cnt[c] = s;
    }
}

// ------- K2: main — in-block center norm, 2-chunk pipeline (NP=4) ------------
__launch_bounds__(256, 2)
__global__ void k_main(const float* __restrict__ x,
                       const float* __restrict__ centers,
                       const int* __restrict__ cnt,
                       const int* __restrict__ idx,
                       float* __restrict__ partials) {
    __shared__ __align__(16) short c_lds[KC * DD];   // 32 KiB bf16, XOR-swizzled
    __shared__ __align__(16) short x_lds[32 * DD];   // 32 KiB bf16, XOR-swizzled
    __shared__ float S_lds[32][33];
    __shared__ float xinv[32];
    __shared__ float red4[4];

    int c = blockIdx.x >> 2;
    int p = blockIdx.x & 3;
    int n = cnt[c];
    int nch = (n + 31) >> 5;
    int t = threadIdx.x, w = t >> 6, lane = t & 63;
    float loss_acc = 0.f;

    if (p < nch) {
        int base = c * BUCKET;
        int row8 = t >> 3, l8 = t & 7;            // 8 threads per (sample|center) row
        int mrow = ((w & 1) << 4) + (lane & 15);
        int nrow = ((w >> 1) << 4) + (lane & 15);

        // ---- issue FIRST chunk's x loads (overlap with center norm below) ----
        float4 xva[8], xvb[8];
        {
            int off = p << 5;
            int rem = n - off;
            int r = (row8 < rem) ? row8 : (rem - 1);
            int g = idx[base + off + r];
            const float4* src = (const float4*)(x + (size_t)g * DD);
#pragma unroll
            for (int jj = 0; jj < 8; jj++) {
                xva[jj] = src[2 * l8 + 16 * jj];
                xvb[jj] = src[2 * l8 + 16 * jj + 1];
            }
        }

        // ---- center norm: batch-load 16 float4, norm, scale, pack, c_lds ----
        {
            const float4* csrc = (const float4*)(centers + ((size_t)c * KC + row8) * DD);
            float4 cva[8], cvb[8];
#pragma unroll
            for (int jj = 0; jj < 8; jj++) {
                cva[jj] = csrc[2 * l8 + 16 * jj];
                cvb[jj] = csrc[2 * l8 + 16 * jj + 1];
            }
            float s = 0.f;
#pragma unroll
            for (int jj = 0; jj < 8; jj++) {
                float4 a = cva[jj], b4 = cvb[jj];
                s += a.x * a.x + a.y * a.y + a.z * a.z + a.w * a.w
                   + b4.x * b4.x + b4.y * b4.y + b4.z * b4.z + b4.w * b4.w;
            }
#pragma unroll
            for (int m = 1; m < 8; m <<= 1) s += __shfl_xor(s, m, 64);
            float sc = rsqrtf(s + 1e-12f);
#pragma unroll
            for (int jj = 0; jj < 8; jj++) {
                int c16 = l8 + 8 * jj;             // 16B bf16 chunk 0..63
                *(short8*)&c_lds[row8 * DD + ((c16 ^ (row8 & 7)) << 3)]
                    = pack8s(sc, cva[jj], cvb[jj]);
            }
        }

        for (int ch = p; ch < nch; ch += NP) {
            int off = ch << 5;
            int rem = n - off;                    // > 0

            // ---- consume prefetched x: norm + cvt + x_lds ----
            {
                float nrm = 0.f;
#pragma unroll
                for (int jj = 0; jj < 8; jj++) {
                    int cc = l8 + 8 * jj;          // 16B bf16 chunk 0..63
                    float4 a = xva[jj], b4 = xvb[jj];
                    nrm += a.x * a.x + a.y * a.y + a.z * a.z + a.w * a.w
                         + b4.x * b4.x + b4.y * b4.y + b4.z * b4.z + b4.w * b4.w;
                    *(short8*)&x_lds[row8 * DD + ((cc ^ (row8 & 7)) << 3)] = pack8(a, b4);
                }
#pragma unroll
                for (int m = 1; m < 8; m <<= 1) nrm += __shfl_xor(nrm, m, 64);
                if (l8 == 0) xinv[row8] = rsqrtf(nrm + 1e-12f);
            }
            __syncthreads();                       // c_lds (1st iter) + x_lds ready

            // ---- MFMA: S[32 samples][32 k] in 4 wave-quadrants ----
            fx4 acc = {0.f, 0.f, 0.f, 0.f};
#pragma unroll
            for (int ks = 0; ks < 16; ks++) {
                int c16a = ks * 4 + (lane >> 4);
                short8 av = *(const short8*)&x_lds[mrow * DD + ((c16a ^ (mrow & 7)) << 3)];
                short8 bv = *(const short8*)&c_lds[nrow * DD + ((c16a ^ (nrow & 7)) << 3)];
                acc = __builtin_amdgcn_mfma_f32_16x16x32_bf16(av, bv, acc, 0, 0, 0);
            }
#pragma unroll
            for (int j = 0; j < 4; j++) {
                int r = ((w & 1) << 4) + ((lane >> 4) << 2) + j;   // C/D row
                int col = ((w >> 1) << 4) + (lane & 15);           // C/D col
                S_lds[r][col] = acc[j];
            }

            // ---- prefetch NEXT chunk's x into registers (survives barriers) --
            if (ch + NP < nch) {
                int off2 = (ch + NP) << 5;
                int rem2 = n - off2;
                int r2 = (row8 < rem2) ? row8 : (rem2 - 1);
                int g2 = idx[base + off2 + r2];
                const float4* src2 = (const float4*)(x + (size_t)g2 * DD);
#pragma unroll
                for (int jj = 0; jj < 8; jj++) {
                    xva[jj] = src2[2 * l8 + 16 * jj];
                    xvb[jj] = src2[2 * l8 + 16 * jj + 1];
                }
            }
            __syncthreads();                       // S_lds ready

            // ---- MAX-FREE softmax over K=32 (cos in [-1,1]; __expf) ----
            {
                float xv = xinv[row8];
                int q4 = l8 << 2;
                float s0 = S_lds[row8][q4 + 0] * xv;
                float s1 = S_lds[row8][q4 + 1] * xv;
                float s2 = S_lds[row8][q4 + 2] * xv;
                float s3 = S_lds[row8][q4 + 3] * xv;
                float e0 = __expf(s0), e1 = __expf(s1);
                float e2 = __expf(s2), e3 = __expf(s3);
                float Z = e0 + e1 + e2 + e3;
                float num = e0 * (1.f - s0) + e1 * (1.f - s1)
                          + e2 * (1.f - s2) + e3 * (1.f - s3);
#pragma unroll
                for (int m = 1; m < 8; m <<= 1) {
                    Z += __shfl_xor(Z, m, 64);
                    num += __shfl_xor(num, m, 64);
                }
                if (l8 == 0 && row8 < rem) loss_acc += num / Z;
            }
            __syncthreads();   // protect x_lds/S_lds before next chunk
        }
    }

    // ---- slim per-wave tail reduce (1 barrier) ----
#pragma unroll
    for (int m = 1; m < 64; m <<= 1) loss_acc += __shfl_xor(loss_acc, m, 64);
    if (lane == 0) red4[w] = loss_acc;
    __syncthreads();
    if (t == 0) partials[blockIdx.x] = red4[0] + red4[1] + red4[2] + red4[3];
}

// ------- K3: deterministic final mean over 360 block partials ----------------
__global__ void k_final(const float* __restrict__ partials, float* __restrict__ out) {
    __shared__ float red[256];
    int t = threadIdx.x;
    float s = 0.f;
    for (int i = t; i < NCLS * NP; i += 256) s += partials[i];
    red[t] = s;
    __syncthreads();
    for (int h = 128; h > 0; h >>= 1) {
        if (t < h) red[t] += red[t + h];
        __syncthreads();
    }
    if (t == 0) out[0] = red[0] * (1.0f / (float)BB);
}

extern "C" void kernel_launch(void* const* d_in, const int* in_sizes, int n_in,
                              void* d_out, int out_size, void* d_ws, size_t ws_size,
                              hipStream_t stream) {
    const float* x       = (const float*)d_in[0];
    const int*   labels  = (const int*)d_in[1];
    const float* centers = (const float*)d_in[2];
    float* out = (float*)d_out;

    char* ws = (char*)d_ws;
    int*   idx      = (int*)(ws + 0);               // 90*512 ints = 184,320 B
    int*   cnt      = (int*)(ws + 184320);          // 90 ints
    float* partials = (float*)(ws + 196608);        // 360 floats (all written)

    k_bin<<<NCLS, 1024, 0, stream>>>(labels, idx, cnt);
    k_main<<<NCLS * NP, 256, 0, stream>>>(x, centers, cnt, idx, partials);
    k_final<<<1, 256, 0, stream>>>(partials, out);
}